// Round 1
// baseline (553.252 us; speedup 1.0000x reference)
//
#include <hip/hip_runtime.h>
#include <hip/hip_bf16.h>
#include <math.h>

// SlotAttention on MI355X.
// Factorization: k,v are never materialized.
//   logits = x @ (Wq^T Wk)^T' path:  qk[b,s,:] = LN(slots)[b,s,:] @ (Wq^T Wk); logits = x·qk
//   updates = (sum_n attn*x) @ Wv^T ; token-normalization 1/(colsum+eps) commutes out.
// Per iteration ONE fused pass over x (bf16, 64MB, L3-resident) does:
//   logits (MFMA) -> softmax over S -> *tw -> colsum (atomic) -> ux += P^T@X (MFMA).

#define EPS_ 1e-8f
#define LNEPS_ 1e-5f

typedef __attribute__((ext_vector_type(8))) short bf16x8;
typedef __attribute__((ext_vector_type(4))) float f32x4;
typedef __attribute__((ext_vector_type(4))) short s16x4;

static __device__ __forceinline__ short f2bf(float f) {
  __hip_bfloat16 h = __float2bfloat16(f);
  union { __hip_bfloat16 h; short s; } u; u.h = h; return u.s;
}
static __device__ __forceinline__ float4 ld4(const float* p){ return *(const float4*)p; }

// ---------------- LayerNorm over D=256, one wave per row ----------------
template<int OBF>
__global__ __launch_bounds__(256) void k_ln_row(const float* __restrict__ in,
    const float* __restrict__ w, const float* __restrict__ b, void* __restrict__ out) {
  int row  = blockIdx.x*4 + (threadIdx.x>>6);
  int lane = threadIdx.x & 63;
  float4 v = ld4(in + (size_t)row*256 + lane*4);
  float s  = v.x+v.y+v.z+v.w;
  float sq = v.x*v.x+v.y*v.y+v.z*v.z+v.w*v.w;
  #pragma unroll
  for (int d=1; d<64; d<<=1) { s += __shfl_xor(s,d); sq += __shfl_xor(sq,d); }
  float mean = s*(1.f/256.f);
  float rstd = rsqrtf(sq*(1.f/256.f) - mean*mean + LNEPS_);
  float4 wv = ld4(w + lane*4), bv = ld4(b + lane*4);
  float o0 = (v.x-mean)*rstd*wv.x + bv.x;
  float o1 = (v.y-mean)*rstd*wv.y + bv.y;
  float o2 = (v.z-mean)*rstd*wv.z + bv.z;
  float o3 = (v.w-mean)*rstd*wv.w + bv.w;
  if (OBF) {
    short4 o; o.x=f2bf(o0); o.y=f2bf(o1); o.z=f2bf(o2); o.w=f2bf(o3);
    *(short4*)((short*)out + (size_t)row*256 + lane*4) = o;
  } else {
    float4 o = make_float4(o0,o1,o2,o3);
    *(float4*)((float*)out + (size_t)row*256 + lane*4) = o;
  }
}

// ---------------- MT = Wq^T @ Wk  (256x256, once) ----------------
__global__ __launch_bounds__(256) void k_mt(const float* __restrict__ Wq,
    const float* __restrict__ Wk, float* __restrict__ MT) {
  int e = blockIdx.x, f = threadIdx.x;
  float acc = 0.f;
  #pragma unroll 4
  for (int d=0; d<256; d++) acc += Wq[d*256+f]*Wk[d*256+e];
  MT[e*256+f] = acc;  // MT[e][f] = sum_d Wq[d][f]*Wk[d][e]  (W-form for k_gemm)
}

// ---------------- slots init ----------------
__global__ __launch_bounds__(256) void k_slots_init(const float* __restrict__ mu,
    const float* __restrict__ ls, const float* __restrict__ noise, float* __restrict__ slots) {
  int i = blockIdx.x*256 + threadIdx.x;       // *4 elements
  int d = (i*4) & 255;
  float4 nz = ld4(noise + (size_t)i*4);
  float4 m  = ld4(mu + d);
  float4 l  = ld4(ls + d);
  float4 o;
  o.x = m.x + fmaxf(__expf(l.x),1e-6f)*nz.x;
  o.y = m.y + fmaxf(__expf(l.y),1e-6f)*nz.y;
  o.z = m.z + fmaxf(__expf(l.z),1e-6f)*nz.z;
  o.w = m.w + fmaxf(__expf(l.w),1e-6f)*nz.w;
  *(float4*)(slots + (size_t)i*4) = o;
}

// ---------------- fused attention pass ----------------
// grid = B*16 blocks (256 rows each), 256 threads = 4 waves.
// Per 64-row group: stage X->LDS, GEMM1 logits (16x16x32 MFMA), wave-parallel
// softmax over S via shfl_xor(w=16), *tw, colsum partials, P->bf16 LDS, GEMM2
// ux-accumulate (held in regs across groups, atomically flushed at end).
__global__ __launch_bounds__(256) void k3_fused(
    const short* __restrict__ x, const short* __restrict__ qk,
    const float* __restrict__ twg, float* __restrict__ ux,
    float* __restrict__ colsum, float* __restrict__ attn_un, int write_attn) {
  __shared__ short Xs[64*264];    // padded: stride 264 elems (528B, 16B-aligned, 2-way max)
  __shared__ short QKs[16*264];
  __shared__ short Pt[16*72];     // P^T: [s][r], stride 72
  __shared__ float tws[64];
  __shared__ float cs[16];
  const int t = threadIdx.x;
  const int b = blockIdx.x >> 4;
  const int n0 = (blockIdx.x & 15) * 256;
  const int lane = t & 63;
  const int w = t >> 6;
  const int l15 = lane & 15;
  const int lg  = lane >> 4;
  #pragma unroll
  for (int i=0;i<2;i++){
    int cid = t + i*256;
    int row = cid>>5, ck = cid&31;
    *(uint4*)&QKs[row*264 + ck*8] = *(const uint4*)&qk[((size_t)(b*16+row))*256 + ck*8];
  }
  if (t<16) cs[t]=0.f;
  f32x4 uacc[4] = {};
  for (int g=0; g<4; ++g) {
    __syncthreads();  // prev group's GEMM2 done with Xs/Pt
    const short* xg = x + ((size_t)b*4096 + n0 + g*64)*256;
    #pragma unroll
    for (int r8=0;r8<8;r8++){
      int row = r8*8 + (t>>5), ck = t&31;
      *(uint4*)&Xs[row*264 + ck*8] = *(const uint4*)&xg[(size_t)row*256 + ck*8];
    }
    if (t<64) tws[t] = fmaxf(twg[(size_t)b*4096 + n0 + g*64 + t], 0.f);
    __syncthreads();
    // GEMM1: rows w*16..w*16+15 of group; D[row][s] = x_row . qk_s
    f32x4 acc = {0.f,0.f,0.f,0.f};
    #pragma unroll
    for (int kk=0;kk<8;kk++){
      bf16x8 af  = *(const bf16x8*)&Xs[(w*16+l15)*264 + kk*32 + lg*8];
      bf16x8 bfr = *(const bf16x8*)&QKs[l15*264 + kk*32 + lg*8];
      acc = __builtin_amdgcn_mfma_f32_16x16x32_bf16(af, bfr, acc, 0,0,0);
    }
    // lane holds s=l15, rows r = w*16 + lg*4 + q
    float a4[4];
    #pragma unroll
    for (int q=0;q<4;q++){
      float v = acc[q]*0.0625f;          // * D^-0.5
      float m = v;
      #pragma unroll
      for (int d=1; d<16; d<<=1) m = fmaxf(m, __shfl_xor(m, d, 16));
      float e = __expf(v-m);
      float se = e;
      #pragma unroll
      for (int d=1; d<16; d<<=1) se += __shfl_xor(se, d, 16);
      int row = w*16 + lg*4 + q;
      float a = (e/se)*tws[row];
      a4[q] = a;
      if (write_attn)
        attn_un[((size_t)b*4096 + n0 + g*64 + row)*16 + l15] = a;
    }
    float psum = a4[0]+a4[1]+a4[2]+a4[3];
    psum += __shfl_xor(psum, 16);
    psum += __shfl_xor(psum, 32);
    if (lane<16) atomicAdd(&cs[l15], psum);
    s16x4 pk; pk[0]=f2bf(a4[0]); pk[1]=f2bf(a4[1]); pk[2]=f2bf(a4[2]); pk[3]=f2bf(a4[3]);
    *(s16x4*)&Pt[l15*72 + w*16 + lg*4] = pk;
    __syncthreads();
    // GEMM2: ux[s][e] += P^T @ X ; wave w owns e-cols [w*64, w*64+64)
    #pragma unroll
    for (int kk=0;kk<2;kk++){
      bf16x8 a2 = *(const bf16x8*)&Pt[l15*72 + kk*32 + lg*8];
      #pragma unroll
      for (int tt=0;tt<4;tt++){
        int col = w*64 + tt*16 + l15;
        int rbv = kk*32 + lg*8;
        bf16x8 b2;
        #pragma unroll
        for (int j=0;j<8;j++) b2[j] = Xs[(rbv+j)*264 + col];
        uacc[tt] = __builtin_amdgcn_mfma_f32_16x16x32_bf16(a2, b2, uacc[tt], 0,0,0);
      }
    }
  }
  __syncthreads();
  if (t<16) atomicAdd(&colsum[b*16+t], cs[t]);
  #pragma unroll
  for (int tt=0;tt<4;tt++){
    #pragma unroll
    for (int q=0;q<4;q++)
      atomicAdd(&ux[((size_t)b*16 + lg*4 + q)*256 + w*64 + tt*16 + l15], uacc[tt][q]);
  }
}

// ---------------- generic fp32 tiled GEMM: C = act(A @ W^T + bias) [+res] ----------------
template<int ACT, int OBF, int RDIV, int RESID>
__global__ __launch_bounds__(256) void k_gemm(const float* __restrict__ A,
    const float* __restrict__ W, const float* __restrict__ bias,
    const float* __restrict__ res, const float* __restrict__ csum,
    void* __restrict__ C, int M, int N, int K, int ldc) {
  __shared__ float As[64][33];
  __shared__ float Ws[64][33];
  const int t = threadIdx.x;
  const int bm = blockIdx.y, bn = blockIdx.x;
  const int rb = (t>>4)<<2, cb = (t&15)<<2;
  float acc[4][4] = {};
  for (int k0=0; k0<K; k0+=32) {
    __syncthreads();
    #pragma unroll
    for (int i=0;i<8;i++){
      int idx = t + i*256;
      int r = idx>>5, kk = idx&31;
      float av = A[(size_t)(bm*64+r)*K + k0 + kk];
      if (RDIV) av *= 1.f/(csum[bm*64+r] + EPS_);
      As[r][kk] = av;
      Ws[r][kk] = W[(size_t)(bn*64+r)*K + k0 + kk];
    }
    __syncthreads();
    #pragma unroll
    for (int kk=0;kk<32;kk++){
      float a0=As[rb][kk],a1=As[rb+1][kk],a2=As[rb+2][kk],a3=As[rb+3][kk];
      float w0=Ws[cb][kk],w1=Ws[cb+1][kk],w2=Ws[cb+2][kk],w3=Ws[cb+3][kk];
      acc[0][0]+=a0*w0; acc[0][1]+=a0*w1; acc[0][2]+=a0*w2; acc[0][3]+=a0*w3;
      acc[1][0]+=a1*w0; acc[1][1]+=a1*w1; acc[1][2]+=a1*w2; acc[1][3]+=a1*w3;
      acc[2][0]+=a2*w0; acc[2][1]+=a2*w1; acc[2][2]+=a2*w2; acc[2][3]+=a2*w3;
      acc[3][0]+=a3*w0; acc[3][1]+=a3*w1; acc[3][2]+=a3*w2; acc[3][3]+=a3*w3;
    }
  }
  #pragma unroll
  for (int i=0;i<4;i++){
    int row = bm*64+rb+i;
    #pragma unroll
    for (int j=0;j<4;j++){
      int col = bn*64+cb+j;
      float v = acc[i][j];
      if (bias) v += bias[col];
      if (ACT) v = 0.5f*v*(1.f+erff(v*0.70710678118654752f));
      if (RESID) v += res[(size_t)row*ldc + col];
      if (OBF) ((__hip_bfloat16*)C)[(size_t)row*ldc + col] = __float2bfloat16(v);
      else     ((float*)C)[(size_t)row*ldc + col] = v;
    }
  }
}

// ---------------- GRU gates + LayerNorm(ln_m) fused, wave per row ----------------
__global__ __launch_bounds__(256) void k_gates(const float* __restrict__ gig,
    const float* __restrict__ lw, const float* __restrict__ lb,
    float* __restrict__ slots, float* __restrict__ lnm) {
  int row  = blockIdx.x*4 + (threadIdx.x>>6);
  int lane = threadIdx.x & 63;
  const float* gi = gig + (size_t)row*1536 + lane*4;
  float4 ir = ld4(gi), iz = ld4(gi+256), inn = ld4(gi+512);
  float4 hr = ld4(gi+768), hz = ld4(gi+1024), hn = ld4(gi+1280);
  float* sp = slots + (size_t)row*256 + lane*4;
  float4 h = ld4(sp);
  float hp[4];
  {
    float r0 = 1.f/(1.f+__expf(-(ir.x+hr.x))); float z0 = 1.f/(1.f+__expf(-(iz.x+hz.x)));
    hp[0] = (1.f-z0)*tanhf(inn.x + r0*hn.x) + z0*h.x;
    float r1 = 1.f/(1.f+__expf(-(ir.y+hr.y))); float z1 = 1.f/(1.f+__expf(-(iz.y+hz.y)));
    hp[1] = (1.f-z1)*tanhf(inn.y + r1*hn.y) + z1*h.y;
    float r2 = 1.f/(1.f+__expf(-(ir.z+hr.z))); float z2 = 1.f/(1.f+__expf(-(iz.z+hz.z)));
    hp[2] = (1.f-z2)*tanhf(inn.z + r2*hn.z) + z2*h.z;
    float r3 = 1.f/(1.f+__expf(-(ir.w+hr.w))); float z3 = 1.f/(1.f+__expf(-(iz.w+hz.w)));
    hp[3] = (1.f-z3)*tanhf(inn.w + r3*hn.w) + z3*h.w;
  }
  float s = hp[0]+hp[1]+hp[2]+hp[3];
  float sq = hp[0]*hp[0]+hp[1]*hp[1]+hp[2]*hp[2]+hp[3]*hp[3];
  #pragma unroll
  for (int d=1; d<64; d<<=1) { s += __shfl_xor(s,d); sq += __shfl_xor(sq,d); }
  float mean = s*(1.f/256.f);
  float rstd = rsqrtf(sq*(1.f/256.f) - mean*mean + LNEPS_);
  float4 wv = ld4(lw+lane*4), bv = ld4(lb+lane*4);
  *(float4*)sp = make_float4(hp[0],hp[1],hp[2],hp[3]);
  *(float4*)(lnm + (size_t)row*256 + lane*4) = make_float4(
      (hp[0]-mean)*rstd*wv.x+bv.x, (hp[1]-mean)*rstd*wv.y+bv.y,
      (hp[2]-mean)*rstd*wv.z+bv.z, (hp[3]-mean)*rstd*wv.w+bv.w);
}

// ---------------- final attn normalization -> d_out ----------------
__global__ __launch_bounds__(256) void k_attn_norm(const float* __restrict__ au,
    const float* __restrict__ cs, float* __restrict__ out) {
  size_t i = ((size_t)blockIdx.x*256 + threadIdx.x)*4;
  float4 v = ld4(au + i);
  int s = (int)(i & 15);
  size_t b = i >> 16;           // 4096*16 elems per batch
  const float* c = cs + b*16 + s;
  float4 o;
  o.x = v.x/(c[0]+EPS_); o.y = v.y/(c[1]+EPS_);
  o.z = v.z/(c[2]+EPS_); o.w = v.w/(c[3]+EPS_);
  *(float4*)(out + i) = o;
}

extern "C" void kernel_launch(void* const* d_in, const int* in_sizes, int n_in,
                              void* d_out, int out_size, void* d_ws, size_t ws_size,
                              hipStream_t stream) {
  const float* inputs   = (const float*)d_in[0];
  const float* token_w  = (const float*)d_in[1];
  const float* noise    = (const float*)d_in[2];
  const float* ln_in_w  = (const float*)d_in[3];
  const float* ln_in_b  = (const float*)d_in[4];
  const float* ln_s_w   = (const float*)d_in[5];
  const float* ln_s_b   = (const float*)d_in[6];
  const float* ln_m_w   = (const float*)d_in[7];
  const float* ln_m_b   = (const float*)d_in[8];
  const float* Wk       = (const float*)d_in[9];
  const float* Wv       = (const float*)d_in[10];
  const float* Wq       = (const float*)d_in[11];
  const float* gru_wih  = (const float*)d_in[12];
  const float* gru_whh  = (const float*)d_in[13];
  const float* gru_bih  = (const float*)d_in[14];
  const float* gru_bhh  = (const float*)d_in[15];
  const float* mlp_w1   = (const float*)d_in[16];
  const float* mlp_b1   = (const float*)d_in[17];
  const float* mlp_w2   = (const float*)d_in[18];
  const float* mlp_b2   = (const float*)d_in[19];
  const float* slots_mu = (const float*)d_in[20];
  const float* slots_ls = (const float*)d_in[21];

  float* out_slots = (float*)d_out;            // [32,16,256]
  float* out_attn  = out_slots + 131072;       // [32,4096,16]

  char* wsb = (char*)d_ws;
  size_t off = 0;
  short* xbf      = (short*)(wsb + off); off += 67108864;   // x bf16 [B,N,D]
  float* attn_un  = (float*)(wsb + off); off += 8388608;    // [B,N,S] f32
  short* qk       = (short*)(wsb + off); off += 262144;     // [B,S,D] bf16
  float* ux       = (float*)(wsb + off); off += 524288;     // [B,S,D] f32 (atomic acc)
  float* colsum   = (float*)(wsb + off); off += 2048;       // [B,S]   (contiguous after ux)
  float* MT       = (float*)(wsb + off); off += 262144;     // Wq^T Wk
  float* xs       = (float*)(wsb + off); off += 524288;     // LN(slots)
  float* updates  = (float*)(wsb + off); off += 524288;
  float* gig      = (float*)(wsb + off); off += 3145728;    // [512][1536] gi|gh
  float* slots    = (float*)(wsb + off); off += 524288;
  float* lnm      = (float*)(wsb + off); off += 524288;
  float* h1       = (float*)(wsb + off); off += 1048576;    // [512][512]

  k_mt<<<256,256,0,stream>>>(Wq, Wk, MT);
  k_slots_init<<<128,256,0,stream>>>(slots_mu, slots_ls, noise, slots);
  k_ln_row<1><<<32768,256,0,stream>>>(inputs, ln_in_w, ln_in_b, (void*)xbf);

  for (int it=0; it<3; ++it) {
    k_ln_row<0><<<128,256,0,stream>>>(slots, ln_s_w, ln_s_b, (void*)xs);
    k_gemm<0,1,0,0><<<dim3(4,8),256,0,stream>>>(xs, MT, nullptr, nullptr, nullptr,
                                                (void*)qk, 512,256,256,256);
    hipMemsetAsync(ux, 0, 524288+2048, stream);   // ux + colsum
    k3_fused<<<512,256,0,stream>>>(xbf, qk, token_w, ux, colsum, attn_un, it==2 ? 1:0);
    k_gemm<0,0,1,0><<<dim3(4,8),256,0,stream>>>(ux, Wv, nullptr, nullptr, colsum,
                                                (void*)updates, 512,256,256,256);
    k_gemm<0,0,0,0><<<dim3(12,8),256,0,stream>>>(updates, gru_wih, gru_bih, nullptr, nullptr,
                                                 (void*)gig, 512,768,256,1536);
    k_gemm<0,0,0,0><<<dim3(12,8),256,0,stream>>>(slots, gru_whh, gru_bhh, nullptr, nullptr,
                                                 (void*)(gig+768), 512,768,256,1536);
    k_gates<<<128,256,0,stream>>>(gig, ln_m_w, ln_m_b, slots, lnm);
    k_gemm<1,0,0,0><<<dim3(8,8),256,0,stream>>>(lnm, mlp_w1, mlp_b1, nullptr, nullptr,
                                                (void*)h1, 512,512,256,512);
    float* cdst = (it==2) ? out_slots : slots;
    k_gemm<0,0,0,1><<<dim3(4,8),256,0,stream>>>(h1, mlp_w2, mlp_b2, slots, nullptr,
                                                (void*)cdst, 512,256,512,256);
  }
  k_attn_norm<<<2048,256,0,stream>>>(attn_un, colsum, out_attn);
}

// Round 2
// 257.350 us; speedup vs baseline: 2.1498x; 2.1498x over previous
//
#include <hip/hip_runtime.h>
#include <hip/hip_bf16.h>
#include <math.h>

// SlotAttention on MI355X.
// Factorization: k,v never materialized.
//   qk[b,s,:] = LN(slots)[b,s,:] @ (Wq^T Wk);  logits = x·qk
//   updates = (sum_n attn*x) @ Wv^T ; token-normalization 1/(colsum+eps) commutes out.
// Per iteration ONE fused pass over x (bf16, 64MB, L3-resident) does:
//   logits (MFMA) -> softmax over S -> *tw -> colsum partial -> ux_part = P^T@X (MFMA).
// All small GEMMs (qk, updates, GRU gi/gh, MLP) are bf16 MFMA with f32 accum.

#define EPS_ 1e-8f
#define LNEPS_ 1e-5f

typedef __attribute__((ext_vector_type(8))) short bf16x8;
typedef __attribute__((ext_vector_type(4))) float f32x4;
typedef __attribute__((ext_vector_type(4))) short s16x4;

static __device__ __forceinline__ short f2bf(float f) {
  __hip_bfloat16 h = __float2bfloat16(f);
  union { __hip_bfloat16 h; short s; } u; u.h = h; return u.s;
}
static __device__ __forceinline__ float4 ld4(const float* p){ return *(const float4*)p; }

// ---------------- LayerNorm over D=256, one wave per row ----------------
template<int OBF>
__global__ __launch_bounds__(256) void k_ln_row(const float* __restrict__ in,
    const float* __restrict__ w, const float* __restrict__ b, void* __restrict__ out) {
  int row  = blockIdx.x*4 + (threadIdx.x>>6);
  int lane = threadIdx.x & 63;
  float4 v = ld4(in + (size_t)row*256 + lane*4);
  float s  = v.x+v.y+v.z+v.w;
  float sq = v.x*v.x+v.y*v.y+v.z*v.z+v.w*v.w;
  #pragma unroll
  for (int d=1; d<64; d<<=1) { s += __shfl_xor(s,d); sq += __shfl_xor(sq,d); }
  float mean = s*(1.f/256.f);
  float rstd = rsqrtf(sq*(1.f/256.f) - mean*mean + LNEPS_);
  float4 wv = ld4(w + lane*4), bv = ld4(b + lane*4);
  float o0 = (v.x-mean)*rstd*wv.x + bv.x;
  float o1 = (v.y-mean)*rstd*wv.y + bv.y;
  float o2 = (v.z-mean)*rstd*wv.z + bv.z;
  float o3 = (v.w-mean)*rstd*wv.w + bv.w;
  if (OBF) {
    short4 o; o.x=f2bf(o0); o.y=f2bf(o1); o.z=f2bf(o2); o.w=f2bf(o3);
    *(short4*)((short*)out + (size_t)row*256 + lane*4) = o;
  } else {
    float4 o = make_float4(o0,o1,o2,o3);
    *(float4*)((float*)out + (size_t)row*256 + lane*4) = o;
  }
}

// ---------------- MT = Wq^T @ Wk  (256x256, once) -> bf16 ----------------
__global__ __launch_bounds__(256) void k_mt(const float* __restrict__ Wq,
    const float* __restrict__ Wk, short* __restrict__ MT) {
  int e = blockIdx.x, f = threadIdx.x;
  float acc = 0.f;
  #pragma unroll 4
  for (int d=0; d<256; d++) acc += Wq[d*256+f]*Wk[d*256+e];
  MT[e*256+f] = f2bf(acc);  // MT[e][f] = sum_d Wq[d][f]*Wk[d][e]  (W-form)
}

// ---------------- cast 5 weight matrices to bf16 ----------------
__global__ __launch_bounds__(256) void k_cast5(
    const float* __restrict__ a0, const float* __restrict__ a1,
    const float* __restrict__ a2, const float* __restrict__ a3,
    const float* __restrict__ a4,
    short* __restrict__ o0, short* __restrict__ o1, short* __restrict__ o2,
    short* __restrict__ o3, short* __restrict__ o4) {
  int c = blockIdx.x*256 + threadIdx.x;  // unit: 4 elems
  const float* src; short* dst;
  if (c < 16384) { src=a0; dst=o0; }
  else if ((c-=16384) < 49152) { src=a1; dst=o1; }
  else if ((c-=49152) < 49152) { src=a2; dst=o2; }
  else if ((c-=49152) < 32768) { src=a3; dst=o3; }
  else { c-=32768; src=a4; dst=o4; }
  float4 v = ld4(src + (size_t)c*4);
  short4 o; o.x=f2bf(v.x); o.y=f2bf(v.y); o.z=f2bf(v.z); o.w=f2bf(v.w);
  *(short4*)(dst + (size_t)c*4) = o;
}

// ---------------- slots init (f32 + bf16 copies) ----------------
__global__ __launch_bounds__(256) void k_slots_init(const float* __restrict__ mu,
    const float* __restrict__ ls, const float* __restrict__ noise,
    float* __restrict__ slots, short* __restrict__ slotsb) {
  int i = blockIdx.x*256 + threadIdx.x;       // *4 elements
  int d = (i*4) & 255;
  float4 nz = ld4(noise + (size_t)i*4);
  float4 m  = ld4(mu + d);
  float4 l  = ld4(ls + d);
  float4 o;
  o.x = m.x + fmaxf(__expf(l.x),1e-6f)*nz.x;
  o.y = m.y + fmaxf(__expf(l.y),1e-6f)*nz.y;
  o.z = m.z + fmaxf(__expf(l.z),1e-6f)*nz.z;
  o.w = m.w + fmaxf(__expf(l.w),1e-6f)*nz.w;
  *(float4*)(slots + (size_t)i*4) = o;
  short4 ob; ob.x=f2bf(o.x); ob.y=f2bf(o.y); ob.z=f2bf(o.z); ob.w=f2bf(o.w);
  *(short4*)(slotsb + (size_t)i*4) = ob;
}

// ---------------- fused attention pass ----------------
// grid = B*16 blocks (256 token-rows each), 256 threads = 4 waves.
// Partial outputs per block: ux_part[block][16][256], colsum_part[block][16].
__global__ __launch_bounds__(256) void k3_fused(
    const short* __restrict__ x, const short* __restrict__ qk,
    const float* __restrict__ twg, float* __restrict__ ux_part,
    float* __restrict__ colsum_part, float* __restrict__ attn_un, int write_attn) {
  __shared__ short Xs[64*264];    // stride 264 elems (528B, 16B-aligned)
  __shared__ short QKs[16*264];
  __shared__ short Pt[16*72];     // P^T: [s][r], stride 72
  __shared__ float tws[64];
  __shared__ float cs[16];
  const int t = threadIdx.x;
  const int b = blockIdx.x >> 4;
  const int n0 = (blockIdx.x & 15) * 256;
  const int lane = t & 63;
  const int w = t >> 6;
  const int l15 = lane & 15;
  const int lg  = lane >> 4;
  #pragma unroll
  for (int i=0;i<2;i++){
    int cid = t + i*256;
    int row = cid>>5, ck = cid&31;
    *(uint4*)&QKs[row*264 + ck*8] = *(const uint4*)&qk[((size_t)(b*16+row))*256 + ck*8];
  }
  if (t<16) cs[t]=0.f;
  f32x4 uacc[4] = {};
  for (int g=0; g<4; ++g) {
    __syncthreads();
    const short* xg = x + ((size_t)b*4096 + n0 + g*64)*256;
    #pragma unroll
    for (int r8=0;r8<8;r8++){
      int row = r8*8 + (t>>5), ck = t&31;
      *(uint4*)&Xs[row*264 + ck*8] = *(const uint4*)&xg[(size_t)row*256 + ck*8];
    }
    if (t<64) tws[t] = fmaxf(twg[(size_t)b*4096 + n0 + g*64 + t], 0.f);
    __syncthreads();
    // GEMM1: D[row][s] = x_row . qk_s
    f32x4 acc = {0.f,0.f,0.f,0.f};
    #pragma unroll
    for (int kk=0;kk<8;kk++){
      bf16x8 af  = *(const bf16x8*)&Xs[(w*16+l15)*264 + kk*32 + lg*8];
      bf16x8 bfr = *(const bf16x8*)&QKs[l15*264 + kk*32 + lg*8];
      acc = __builtin_amdgcn_mfma_f32_16x16x32_bf16(af, bfr, acc, 0,0,0);
    }
    float a4[4];
    #pragma unroll
    for (int q=0;q<4;q++){
      float v = acc[q]*0.0625f;          // * D^-0.5
      float m = v;
      #pragma unroll
      for (int d=1; d<16; d<<=1) m = fmaxf(m, __shfl_xor(m, d, 16));
      float e = __expf(v-m);
      float se = e;
      #pragma unroll
      for (int d=1; d<16; d<<=1) se += __shfl_xor(se, d, 16);
      int row = w*16 + lg*4 + q;
      float a = (e/se)*tws[row];
      a4[q] = a;
      if (write_attn)
        attn_un[((size_t)b*4096 + n0 + g*64 + row)*16 + l15] = a;
    }
    float psum = a4[0]+a4[1]+a4[2]+a4[3];
    psum += __shfl_xor(psum, 16);
    psum += __shfl_xor(psum, 32);
    if (lane<16) atomicAdd(&cs[l15], psum);
    s16x4 pk; pk[0]=f2bf(a4[0]); pk[1]=f2bf(a4[1]); pk[2]=f2bf(a4[2]); pk[3]=f2bf(a4[3]);
    *(s16x4*)&Pt[l15*72 + w*16 + lg*4] = pk;
    __syncthreads();
    // GEMM2: ux[s][e] += P^T @ X ; wave w owns e-cols [w*64, w*64+64)
    #pragma unroll
    for (int kk=0;kk<2;kk++){
      bf16x8 a2 = *(const bf16x8*)&Pt[l15*72 + kk*32 + lg*8];
      #pragma unroll
      for (int tt=0;tt<4;tt++){
        int col = w*64 + tt*16 + l15;
        int rbv = kk*32 + lg*8;
        bf16x8 b2;
        #pragma unroll
        for (int j=0;j<8;j++) b2[j] = Xs[(rbv+j)*264 + col];
        uacc[tt] = __builtin_amdgcn_mfma_f32_16x16x32_bf16(a2, b2, uacc[tt], 0,0,0);
      }
    }
  }
  __syncthreads();
  if (t<16) colsum_part[blockIdx.x*16 + t] = cs[t];
  #pragma unroll
  for (int tt=0;tt<4;tt++){
    #pragma unroll
    for (int q=0;q<4;q++)
      ux_part[(size_t)blockIdx.x*4096 + (lg*4+q)*256 + w*64 + tt*16 + l15] = uacc[tt][q];
  }
}

// ---------------- reduce ux partials (+fold 1/(colsum+eps)) -> bf16 ----------------
__global__ __launch_bounds__(256) void k_reduce(const float* __restrict__ uxp,
    const float* __restrict__ csp, short* __restrict__ uxr, float* __restrict__ csr) {
  int r = blockIdx.x;          // b*16+s
  int b = r>>4, s = r&15;
  int t = threadIdx.x;
  float cs = 0.f;
  #pragma unroll
  for (int k=0;k<16;k++) cs += csp[((b<<4)+k)*16 + s];
  float u = 0.f;
  #pragma unroll
  for (int k=0;k<16;k++) u += uxp[(size_t)((b<<4)+k)*4096 + s*256 + t];
  uxr[(size_t)r*256+t] = f2bf(u/(cs+EPS_));
  if (t==0) csr[r] = cs;
}

// ---------------- bf16 MFMA GEMM: out = epi(A @ W^T + bias) ----------------
// A: bf16 [M,K] rm; W: bf16 [N,K] rm. grid (N/64, M/64 [,2]); 256 thr.
// EPI: 0 bf16 out; 1 gelu->bf16; 2 f32 out; 3 residual(f32)+f32 out + bf16 out2.
template<int EPI, int ZSEL>
__global__ __launch_bounds__(256) void k_mgemm(
    const short* __restrict__ A, const short* __restrict__ W,
    const float* __restrict__ bias, const float* __restrict__ res,
    float* __restrict__ outf, short* __restrict__ outb,
    const short* __restrict__ A2, const short* __restrict__ W2,
    const float* __restrict__ bias2, int K, int ldc) {
  __shared__ short As[64*56];   // stride 56 shorts = 112 B (16B-aligned, 2-way banks)
  __shared__ short Ws[64*56];
  if (ZSEL && blockIdx.z) { A=A2; W=W2; bias=bias2; outf += 768; }
  const int t = threadIdx.x;
  const int bm = blockIdx.y, bn = blockIdx.x;
  const int w = t>>6, lane = t&63, l15 = lane&15, lg = lane>>4;
  const int srow = t>>2, scol = (t&3)*8;
  f32x4 acc[4] = {};
  for (int k0=0; k0<K; k0+=32) {
    __syncthreads();
    *(uint4*)&As[srow*56 + scol] = *(const uint4*)&A[(size_t)(bm*64+srow)*K + k0 + scol];
    *(uint4*)&Ws[srow*56 + scol] = *(const uint4*)&W[(size_t)(bn*64+srow)*K + k0 + scol];
    __syncthreads();
    bf16x8 af = *(const bf16x8*)&As[(w*16+l15)*56 + lg*8];
    #pragma unroll
    for (int ct=0; ct<4; ct++) {
      bf16x8 bfr = *(const bf16x8*)&Ws[(ct*16+l15)*56 + lg*8];
      acc[ct] = __builtin_amdgcn_mfma_f32_16x16x32_bf16(af, bfr, acc[ct], 0,0,0);
    }
  }
  #pragma unroll
  for (int ct=0; ct<4; ct++) {
    int col = bn*64 + ct*16 + l15;
    float bv = bias ? bias[col] : 0.f;
    #pragma unroll
    for (int q=0; q<4; q++) {
      int row = bm*64 + w*16 + lg*4 + q;
      float v = acc[ct][q] + bv;
      if (EPI==1) v = 0.5f*v*(1.f+erff(v*0.70710678118654752f));
      if (EPI==3) v += res[(size_t)row*ldc + col];
      if (EPI==0 || EPI==1) {
        outb[(size_t)row*ldc + col] = f2bf(v);
      } else {
        outf[(size_t)row*ldc + col] = v;
        if (EPI==3) outb[(size_t)row*ldc + col] = f2bf(v);
      }
    }
  }
}

// ---------------- GRU gates + LayerNorm(ln_m) fused, wave per row ----------------
__global__ __launch_bounds__(256) void k_gates(const float* __restrict__ gig,
    const float* __restrict__ lw, const float* __restrict__ lb,
    float* __restrict__ slots, short* __restrict__ lnmb) {
  int row  = blockIdx.x*4 + (threadIdx.x>>6);
  int lane = threadIdx.x & 63;
  const float* gi = gig + (size_t)row*1536 + lane*4;
  float4 ir = ld4(gi), iz = ld4(gi+256), inn = ld4(gi+512);
  float4 hr = ld4(gi+768), hz = ld4(gi+1024), hn = ld4(gi+1280);
  float* sp = slots + (size_t)row*256 + lane*4;
  float4 h = ld4(sp);
  float hp[4];
  {
    float r0 = 1.f/(1.f+__expf(-(ir.x+hr.x))); float z0 = 1.f/(1.f+__expf(-(iz.x+hz.x)));
    hp[0] = (1.f-z0)*tanhf(inn.x + r0*hn.x) + z0*h.x;
    float r1 = 1.f/(1.f+__expf(-(ir.y+hr.y))); float z1 = 1.f/(1.f+__expf(-(iz.y+hz.y)));
    hp[1] = (1.f-z1)*tanhf(inn.y + r1*hn.y) + z1*h.y;
    float r2 = 1.f/(1.f+__expf(-(ir.z+hr.z))); float z2 = 1.f/(1.f+__expf(-(iz.z+hz.z)));
    hp[2] = (1.f-z2)*tanhf(inn.z + r2*hn.z) + z2*h.z;
    float r3 = 1.f/(1.f+__expf(-(ir.w+hr.w))); float z3 = 1.f/(1.f+__expf(-(iz.w+hz.w)));
    hp[3] = (1.f-z3)*tanhf(inn.w + r3*hn.w) + z3*h.w;
  }
  float s = hp[0]+hp[1]+hp[2]+hp[3];
  float sq = hp[0]*hp[0]+hp[1]*hp[1]+hp[2]*hp[2]+hp[3]*hp[3];
  #pragma unroll
  for (int d=1; d<64; d<<=1) { s += __shfl_xor(s,d); sq += __shfl_xor(sq,d); }
  float mean = s*(1.f/256.f);
  float rstd = rsqrtf(sq*(1.f/256.f) - mean*mean + LNEPS_);
  float4 wv = ld4(lw+lane*4), bv = ld4(lb+lane*4);
  *(float4*)sp = make_float4(hp[0],hp[1],hp[2],hp[3]);
  short4 o;
  o.x = f2bf((hp[0]-mean)*rstd*wv.x+bv.x);
  o.y = f2bf((hp[1]-mean)*rstd*wv.y+bv.y);
  o.z = f2bf((hp[2]-mean)*rstd*wv.z+bv.z);
  o.w = f2bf((hp[3]-mean)*rstd*wv.w+bv.w);
  *(short4*)(lnmb + (size_t)row*256 + lane*4) = o;
}

// ---------------- final attn normalization -> d_out ----------------
__global__ __launch_bounds__(256) void k_attn_norm(const float* __restrict__ au,
    const float* __restrict__ cs, float* __restrict__ out) {
  size_t i = ((size_t)blockIdx.x*256 + threadIdx.x)*4;
  float4 v = ld4(au + i);
  int s = (int)(i & 15);
  size_t b = i >> 16;           // 4096*16 elems per batch
  const float* c = cs + b*16 + s;
  float4 o;
  o.x = v.x/(c[0]+EPS_); o.y = v.y/(c[1]+EPS_);
  o.z = v.z/(c[2]+EPS_); o.w = v.w/(c[3]+EPS_);
  *(float4*)(out + i) = o;
}

extern "C" void kernel_launch(void* const* d_in, const int* in_sizes, int n_in,
                              void* d_out, int out_size, void* d_ws, size_t ws_size,
                              hipStream_t stream) {
  const float* inputs   = (const float*)d_in[0];
  const float* token_w  = (const float*)d_in[1];
  const float* noise    = (const float*)d_in[2];
  const float* ln_in_w  = (const float*)d_in[3];
  const float* ln_in_b  = (const float*)d_in[4];
  const float* ln_s_w   = (const float*)d_in[5];
  const float* ln_s_b   = (const float*)d_in[6];
  const float* ln_m_w   = (const float*)d_in[7];
  const float* ln_m_b   = (const float*)d_in[8];
  const float* Wk       = (const float*)d_in[9];
  const float* Wv       = (const float*)d_in[10];
  const float* Wq       = (const float*)d_in[11];
  const float* gru_wih  = (const float*)d_in[12];
  const float* gru_whh  = (const float*)d_in[13];
  const float* gru_bih  = (const float*)d_in[14];
  const float* gru_bhh  = (const float*)d_in[15];
  const float* mlp_w1   = (const float*)d_in[16];
  const float* mlp_b1   = (const float*)d_in[17];
  const float* mlp_w2   = (const float*)d_in[18];
  const float* mlp_b2   = (const float*)d_in[19];
  const float* slots_mu = (const float*)d_in[20];
  const float* slots_ls = (const float*)d_in[21];

  float* out_slots = (float*)d_out;            // [32,16,256]
  float* out_attn  = out_slots + 131072;       // [32,4096,16]

  char* wsb = (char*)d_ws;
  size_t off = 0;
  short* xbf     = (short*)(wsb + off); off += 67108864;   // x bf16 [B,N,D]
  float* attn_un = (float*)(wsb + off); off += 8388608;    // [B,N,S] f32
  float* ux_part = (float*)(wsb + off); off += 8388608;    // [512][16][256] f32
  float* cs_part = (float*)(wsb + off); off += 32768;      // [512][16]
  float* cs_red  = (float*)(wsb + off); off += 2048;       // [B*S]
  short* qk      = (short*)(wsb + off); off += 262144;     // [B,S,D] bf16
  short* uxr     = (short*)(wsb + off); off += 262144;     // reduced ux / colsum, bf16
  short* MTb     = (short*)(wsb + off); off += 131072;     // Wq^T Wk bf16
  short* lnS     = (short*)(wsb + off); off += 262144;     // LN_s(slots) bf16
  short* updb    = (short*)(wsb + off); off += 262144;     // updates bf16
  float* gig     = (float*)(wsb + off); off += 3145728;    // [512][1536] gi|gh f32
  float* slots   = (float*)(wsb + off); off += 524288;     // slots f32
  short* slotsb  = (short*)(wsb + off); off += 262144;     // slots bf16
  short* lnmb    = (short*)(wsb + off); off += 262144;     // LN_m bf16
  short* hb      = (short*)(wsb + off); off += 524288;     // mlp hidden bf16 [512][512]
  short* Wvb     = (short*)(wsb + off); off += 131072;
  short* wihb    = (short*)(wsb + off); off += 393216;
  short* whhb    = (short*)(wsb + off); off += 393216;
  short* w1b     = (short*)(wsb + off); off += 262144;
  short* w2b     = (short*)(wsb + off); off += 262144;

  k_mt<<<256,256,0,stream>>>(Wq, Wk, MTb);
  k_cast5<<<704,256,0,stream>>>(Wv, gru_wih, gru_whh, mlp_w1, mlp_w2,
                                Wvb, wihb, whhb, w1b, w2b);
  k_slots_init<<<128,256,0,stream>>>(slots_mu, slots_ls, noise, slots, slotsb);
  k_ln_row<1><<<32768,256,0,stream>>>(inputs, ln_in_w, ln_in_b, (void*)xbf);

  // qk_0
  k_ln_row<1><<<128,256,0,stream>>>(slots, ln_s_w, ln_s_b, (void*)lnS);
  k_mgemm<0,0><<<dim3(4,8),256,0,stream>>>(lnS, MTb, nullptr, nullptr, nullptr, qk,
                                           nullptr, nullptr, nullptr, 256, 256);
  for (int it=0; it<3; ++it) {
    k3_fused<<<512,256,0,stream>>>(xbf, qk, token_w, ux_part, cs_part, attn_un, it==2 ? 1:0);
    k_reduce<<<512,256,0,stream>>>(ux_part, cs_part, uxr, cs_red);
    k_mgemm<0,0><<<dim3(4,8),256,0,stream>>>(uxr, Wvb, nullptr, nullptr, nullptr, updb,
                                             nullptr, nullptr, nullptr, 256, 256);
    k_mgemm<2,1><<<dim3(12,8,2),256,0,stream>>>(updb, wihb, gru_bih, nullptr, gig, nullptr,
                                                slotsb, whhb, gru_bhh, 256, 1536);
    k_gates<<<128,256,0,stream>>>(gig, ln_m_w, ln_m_b, slots, lnmb);
    k_mgemm<1,0><<<dim3(8,8),256,0,stream>>>(lnmb, w1b, mlp_b1, nullptr, nullptr, hb,
                                             nullptr, nullptr, nullptr, 256, 512);
    float* cdst = (it==2) ? out_slots : slots;
    k_mgemm<3,0><<<dim3(4,8),256,0,stream>>>(hb, w2b, mlp_b2, slots, cdst, slotsb,
                                             nullptr, nullptr, nullptr, 512, 256);
    if (it<2) {
      k_ln_row<1><<<128,256,0,stream>>>(slots, ln_s_w, ln_s_b, (void*)lnS);
      k_mgemm<0,0><<<dim3(4,8),256,0,stream>>>(lnS, MTb, nullptr, nullptr, nullptr, qk,
                                               nullptr, nullptr, nullptr, 256, 256);
    }
  }
  k_attn_norm<<<2048,256,0,stream>>>(attn_un, cs_red, out_attn);
}

// Round 4
// 241.302 us; speedup vs baseline: 2.2928x; 1.0665x over previous
//
#include <hip/hip_runtime.h>
#include <hip/hip_bf16.h>
#include <math.h>

// SlotAttention on MI355X.
// Factorizations:
//   k,v never materialized:  qk = LN(slots) @ (Wq^T Wk);  logits = x·qk
//   updates feeds only the GRU input GEMM:  gi = uxr @ (wih·Wv)^T  (M precomputed)
//   token-normalization 1/(colsum+eps) commutes out of the P^T@X accumulation.
// Iteration = k3 (fused attention pass over x) -> reduce -> gigh -> gates -> mlp1 -> slotend.
// k3 iter0 performs LN(inputs) in-register and emits xbf as a by-product.

#define EPS_ 1e-8f
#define LNEPS_ 1e-5f

typedef __attribute__((ext_vector_type(8))) short bf16x8;
typedef __attribute__((ext_vector_type(4))) float f32x4;
typedef __attribute__((ext_vector_type(4))) short s16x4;

static __device__ __forceinline__ short f2bf(float f) {
  __hip_bfloat16 h = __float2bfloat16(f);
  union { __hip_bfloat16 h; short s; } u; u.h = h; return u.s;
}
static __device__ __forceinline__ float4 ld4(const float* p){ return *(const float4*)p; }

// ---------------- prep: MT = Wq^T Wk, M = wih@Wv, bf16 casts ----------------
__global__ __launch_bounds__(256) void k_prep(
    const float* __restrict__ Wq, const float* __restrict__ Wk,
    const float* __restrict__ wih, const float* __restrict__ Wv,
    const float* __restrict__ whh, const float* __restrict__ w1, const float* __restrict__ w2,
    short* __restrict__ MTb, short* __restrict__ Mb, short* __restrict__ whhb,
    short* __restrict__ w1b, short* __restrict__ w2b) {
  int blk = blockIdx.x, t = threadIdx.x;
  if (blk < 64) {                 // MT[e][f] = sum_d Wq[d][f]*Wk[d][e], 4 e per block
    int e0 = blk*4;
    float a0=0,a1=0,a2=0,a3=0;
    for (int d=0; d<256; d++) {
      float qv = Wq[d*256 + t];
      a0 += qv*Wk[d*256+e0];   a1 += qv*Wk[d*256+e0+1];
      a2 += qv*Wk[d*256+e0+2]; a3 += qv*Wk[d*256+e0+3];
    }
    MTb[(e0  )*256+t]=f2bf(a0); MTb[(e0+1)*256+t]=f2bf(a1);
    MTb[(e0+2)*256+t]=f2bf(a2); MTb[(e0+3)*256+t]=f2bf(a3);
  } else if (blk < 256) {         // M[n][e] = sum_d wih[n][d]*Wv[d][e], 4 n per block
    int n0 = (blk-64)*4;
    float a0=0,a1=0,a2=0,a3=0;
    for (int d=0; d<256; d++) {
      float vv = Wv[d*256 + t];
      a0 += wih[(n0  )*256+d]*vv; a1 += wih[(n0+1)*256+d]*vv;
      a2 += wih[(n0+2)*256+d]*vv; a3 += wih[(n0+3)*256+d]*vv;
    }
    Mb[(size_t)(n0  )*256+t]=f2bf(a0); Mb[(size_t)(n0+1)*256+t]=f2bf(a1);
    Mb[(size_t)(n0+2)*256+t]=f2bf(a2); Mb[(size_t)(n0+3)*256+t]=f2bf(a3);
  } else {                        // casts: whh 49152, w1 32768, w2 32768 float4s
    int c = (blk-256)*256 + t;
    const float* src; short* dst;
    if (c < 49152) { src=whh; dst=whhb; }
    else if ((c-=49152) < 32768) { src=w1; dst=w1b; }
    else { c-=32768; src=w2; dst=w2b; }
    float4 v = ld4(src + (size_t)c*4);
    short4 o; o.x=f2bf(v.x); o.y=f2bf(v.y); o.z=f2bf(v.z); o.w=f2bf(v.w);
    *(short4*)(dst + (size_t)c*4) = o;
  }
}

// ---------------- fused attention pass (+optional LN-of-inputs) ----------------
// grid = B*16 blocks (256 token-rows each), 256 threads = 4 waves.
template<int LNIN, int WATTN>
__global__ __launch_bounds__(256) void k3(
    const float* __restrict__ inputs, const float* __restrict__ lnw, const float* __restrict__ lnb,
    short* __restrict__ xbf, const short* __restrict__ qk, const float* __restrict__ twg,
    float* __restrict__ ux_part, float* __restrict__ colsum_part, float* __restrict__ attn_un) {
  __shared__ short Xs[64*264];
  __shared__ short QKs[16*264];
  __shared__ short Pt[16*72];
  __shared__ float tws[64];
  __shared__ float cs[16];
  __shared__ float lnwb[512];
  const int t = threadIdx.x;
  const int b = blockIdx.x >> 4;
  const int n0 = (blockIdx.x & 15) * 256;
  const int lane = t & 63, w = t >> 6, l15 = lane & 15, lg = lane >> 4;
  #pragma unroll
  for (int i=0;i<2;i++){
    int cid = t + i*256;
    int row = cid>>5, ck = cid&31;
    *(uint4*)&QKs[row*264 + ck*8] = *(const uint4*)&qk[((size_t)(b*16+row))*256 + ck*8];
  }
  if (LNIN){
    if (t < 64)       *(float4*)&lnwb[t*4]           = ld4(lnw + t*4);
    else if (t < 128) *(float4*)&lnwb[256+(t-64)*4]  = ld4(lnb + (t-64)*4);
  }
  if (t<16) cs[t]=0.f;
  f32x4 uacc[4] = {};
  for (int g=0; g<4; ++g) {
    __syncthreads();
    const size_t rowbase = (size_t)b*4096 + n0 + g*64;
    if (LNIN) {
      // LN(inputs) in-register: 4 lanes per row, each 16 float4 (interleaved chunks)
      const float* ing = inputs + rowbase*256;
      const int r = t>>2, c = t&3;
      float4 vv[16];
      #pragma unroll
      for (int k=0;k<16;k++) vv[k] = ld4(ing + r*256 + (c+4*k)*4);
      float s=0.f, sq=0.f;
      #pragma unroll
      for (int k=0;k<16;k++){
        s  += vv[k].x+vv[k].y+vv[k].z+vv[k].w;
        sq += vv[k].x*vv[k].x+vv[k].y*vv[k].y+vv[k].z*vv[k].z+vv[k].w*vv[k].w;
      }
      s += __shfl_xor(s,1);  s += __shfl_xor(s,2);
      sq += __shfl_xor(sq,1); sq += __shfl_xor(sq,2);
      float mean = s*(1.f/256.f);
      float rstd = rsqrtf(sq*(1.f/256.f) - mean*mean + LNEPS_);
      short* xw = xbf + rowbase*256;
      #pragma unroll
      for (int k=0;k<16;k++){
        int d0 = (c+4*k)*4;
        float4 wv = *(float4*)&lnwb[d0];
        float4 bv = *(float4*)&lnwb[256+d0];
        s16x4 pk;
        pk[0]=f2bf((vv[k].x-mean)*rstd*wv.x+bv.x);
        pk[1]=f2bf((vv[k].y-mean)*rstd*wv.y+bv.y);
        pk[2]=f2bf((vv[k].z-mean)*rstd*wv.z+bv.z);
        pk[3]=f2bf((vv[k].w-mean)*rstd*wv.w+bv.w);
        *(s16x4*)&Xs[r*264 + d0] = pk;
        *(s16x4*)&xw[r*256 + d0] = pk;
      }
    } else {
      const short* xg = xbf + rowbase*256;
      #pragma unroll
      for (int r8=0;r8<8;r8++){
        int row = r8*8 + (t>>5), ck = t&31;
        *(uint4*)&Xs[row*264 + ck*8] = *(const uint4*)&xg[(size_t)row*256 + ck*8];
      }
    }
    if (t<64) tws[t] = fmaxf(twg[rowbase + t], 0.f);
    __syncthreads();
    // GEMM1: D[row][s] = x_row . qk_s
    f32x4 acc = {0.f,0.f,0.f,0.f};
    #pragma unroll
    for (int kk=0;kk<8;kk++){
      bf16x8 af  = *(const bf16x8*)&Xs[(w*16+l15)*264 + kk*32 + lg*8];
      bf16x8 bfr = *(const bf16x8*)&QKs[l15*264 + kk*32 + lg*8];
      acc = __builtin_amdgcn_mfma_f32_16x16x32_bf16(af, bfr, acc, 0,0,0);
    }
    float a4[4];
    #pragma unroll
    for (int q=0;q<4;q++){
      float v = acc[q]*0.0625f;          // * D^-0.5
      float m = v;
      #pragma unroll
      for (int d=1; d<16; d<<=1) m = fmaxf(m, __shfl_xor(m, d, 16));
      float e = __expf(v-m);
      float se = e;
      #pragma unroll
      for (int d=1; d<16; d<<=1) se += __shfl_xor(se, d, 16);
      int row = w*16 + lg*4 + q;
      float a = (e/se)*tws[row];
      a4[q] = a;
      if (WATTN)
        attn_un[(rowbase + row)*16 + l15] = a;
    }
    float psum = a4[0]+a4[1]+a4[2]+a4[3];
    psum += __shfl_xor(psum, 16);
    psum += __shfl_xor(psum, 32);
    if (lane<16) atomicAdd(&cs[l15], psum);
    s16x4 pk; pk[0]=f2bf(a4[0]); pk[1]=f2bf(a4[1]); pk[2]=f2bf(a4[2]); pk[3]=f2bf(a4[3]);
    *(s16x4*)&Pt[l15*72 + w*16 + lg*4] = pk;
    __syncthreads();
    // GEMM2: ux[s][e] += P^T @ X ; wave w owns e-cols [w*64, w*64+64)
    #pragma unroll
    for (int kk=0;kk<2;kk++){
      bf16x8 a2 = *(const bf16x8*)&Pt[l15*72 + kk*32 + lg*8];
      #pragma unroll
      for (int tt=0;tt<4;tt++){
        int col = w*64 + tt*16 + l15;
        int rbv = kk*32 + lg*8;
        bf16x8 b2;
        #pragma unroll
        for (int j=0;j<8;j++) b2[j] = Xs[(rbv+j)*264 + col];
        uacc[tt] = __builtin_amdgcn_mfma_f32_16x16x32_bf16(a2, b2, uacc[tt], 0,0,0);
      }
    }
  }
  __syncthreads();
  if (t<16) colsum_part[blockIdx.x*16 + t] = cs[t];
  #pragma unroll
  for (int tt=0;tt<4;tt++){
    #pragma unroll
    for (int q=0;q<4;q++)
      ux_part[(size_t)blockIdx.x*4096 + (lg*4+q)*256 + w*64 + tt*16 + l15] = uacc[tt][q];
  }
}

// ---------------- reduce ux partials (+fold 1/(colsum+eps)) -> bf16 ----------------
__global__ __launch_bounds__(256) void k_reduce(const float* __restrict__ uxp,
    const float* __restrict__ csp, short* __restrict__ uxr, float* __restrict__ csr) {
  int r = blockIdx.x;          // b*16+s
  int b = r>>4, s = r&15;
  int t = threadIdx.x;
  float cs = 0.f;
  #pragma unroll
  for (int k=0;k<16;k++) cs += csp[((b<<4)+k)*16 + s];
  float u = 0.f;
  #pragma unroll
  for (int k=0;k<16;k++) u += uxp[(size_t)((b<<4)+k)*4096 + s*256 + t];
  uxr[(size_t)r*256+t] = f2bf(u/(cs+EPS_));
  if (t==0) csr[r] = cs;
}

// ---------------- gi|gh GEMM: gig[row][0:768]=uxr@M^T+bih, [768:1536]=slotsb@whh^T+bhh ----
__global__ __launch_bounds__(256) void k_gigh(
    const short* __restrict__ uxr, const short* __restrict__ slotsb,
    const short* __restrict__ Mb, const short* __restrict__ whhb,
    const float* __restrict__ bih, const float* __restrict__ bhh,
    float* __restrict__ gig) {
  __shared__ short As[64*40];
  __shared__ short Ws[64*40];
  const int t=threadIdx.x, bn=blockIdx.x, bm=blockIdx.y;
  const short* A; const short* W; const float* bias; int wo;
  if (bn<12) { A=uxr;    W=Mb   + (size_t)bn*64*256;      bias=bih; wo=bn*64; }
  else       { A=slotsb; W=whhb + (size_t)(bn-12)*64*256; bias=bhh; wo=(bn-12)*64; }
  const int w=t>>6, lane=t&63, l15=lane&15, lg=lane>>4;
  f32x4 acc[4]={};
  for (int k0=0;k0<256;k0+=32){
    __syncthreads();
    *(uint4*)&As[(t>>2)*40+(t&3)*8] = *(const uint4*)&A[(size_t)(bm*64+(t>>2))*256 + k0 + (t&3)*8];
    *(uint4*)&Ws[(t>>2)*40+(t&3)*8] = *(const uint4*)&W[(size_t)(t>>2)*256 + k0 + (t&3)*8];
    __syncthreads();
    bf16x8 af = *(const bf16x8*)&As[(w*16+l15)*40+lg*8];
    #pragma unroll
    for (int ct=0;ct<4;ct++){
      bf16x8 bfr = *(const bf16x8*)&Ws[(ct*16+l15)*40+lg*8];
      acc[ct]=__builtin_amdgcn_mfma_f32_16x16x32_bf16(af,bfr,acc[ct],0,0,0);
    }
  }
  #pragma unroll
  for (int ct=0;ct<4;ct++){
    float bv = bias[wo + ct*16 + l15];
    #pragma unroll
    for (int q=0;q<4;q++){
      int row = bm*64 + w*16 + lg*4 + q;
      gig[(size_t)row*1536 + bn*64 + ct*16 + l15] = acc[ct][q] + bv;
    }
  }
}

// ---------------- MLP1: hb = gelu(lnmb @ w1^T + b1), bf16 ----------------
__global__ __launch_bounds__(256) void k_mlp1(
    const short* __restrict__ lnmb, const short* __restrict__ w1b,
    const float* __restrict__ b1, short* __restrict__ hb) {
  __shared__ short As[64*40];
  __shared__ short Ws[64*40];
  const int t=threadIdx.x, bn=blockIdx.x, bm=blockIdx.y;
  const int w=t>>6, lane=t&63, l15=lane&15, lg=lane>>4;
  f32x4 acc[4]={};
  for (int k0=0;k0<256;k0+=32){
    __syncthreads();
    *(uint4*)&As[(t>>2)*40+(t&3)*8] = *(const uint4*)&lnmb[(size_t)(bm*64+(t>>2))*256 + k0 + (t&3)*8];
    *(uint4*)&Ws[(t>>2)*40+(t&3)*8] = *(const uint4*)&w1b[(size_t)(bn*64+(t>>2))*256 + k0 + (t&3)*8];
    __syncthreads();
    bf16x8 af = *(const bf16x8*)&As[(w*16+l15)*40+lg*8];
    #pragma unroll
    for (int ct=0;ct<4;ct++){
      bf16x8 bfr = *(const bf16x8*)&Ws[(ct*16+l15)*40+lg*8];
      acc[ct]=__builtin_amdgcn_mfma_f32_16x16x32_bf16(af,bfr,acc[ct],0,0,0);
    }
  }
  #pragma unroll
  for (int ct=0;ct<4;ct++){
    float bv = b1[bn*64 + ct*16 + l15];
    #pragma unroll
    for (int q=0;q<4;q++){
      int row = bm*64 + w*16 + lg*4 + q;
      float v = acc[ct][q] + bv;
      v = 0.5f*v*(1.f+erff(v*0.70710678118654752f));
      hb[(size_t)row*512 + bn*64 + ct*16 + l15] = f2bf(v);
    }
  }
}

// ---------------- GRU gates + LayerNorm(ln_m), wave per row ----------------
__global__ __launch_bounds__(256) void k_gates(const float* __restrict__ gig,
    const float* __restrict__ lw, const float* __restrict__ lb,
    float* __restrict__ slots, short* __restrict__ lnmb) {
  int row  = blockIdx.x*4 + (threadIdx.x>>6);
  int lane = threadIdx.x & 63;
  const float* gi = gig + (size_t)row*1536 + lane*4;
  float4 ir = ld4(gi), iz = ld4(gi+256), inn = ld4(gi+512);
  float4 hr = ld4(gi+768), hz = ld4(gi+1024), hn = ld4(gi+1280);
  float* sp = slots + (size_t)row*256 + lane*4;
  float4 h = ld4(sp);
  float hp[4];
  {
    float r0 = 1.f/(1.f+__expf(-(ir.x+hr.x))); float z0 = 1.f/(1.f+__expf(-(iz.x+hz.x)));
    hp[0] = (1.f-z0)*tanhf(inn.x + r0*hn.x) + z0*h.x;
    float r1 = 1.f/(1.f+__expf(-(ir.y+hr.y))); float z1 = 1.f/(1.f+__expf(-(iz.y+hz.y)));
    hp[1] = (1.f-z1)*tanhf(inn.y + r1*hn.y) + z1*h.y;
    float r2 = 1.f/(1.f+__expf(-(ir.z+hr.z))); float z2 = 1.f/(1.f+__expf(-(iz.z+hz.z)));
    hp[2] = (1.f-z2)*tanhf(inn.z + r2*hn.z) + z2*h.z;
    float r3 = 1.f/(1.f+__expf(-(ir.w+hr.w))); float z3 = 1.f/(1.f+__expf(-(iz.w+hz.w)));
    hp[3] = (1.f-z3)*tanhf(inn.w + r3*hn.w) + z3*h.w;
  }
  float s = hp[0]+hp[1]+hp[2]+hp[3];
  float sq = hp[0]*hp[0]+hp[1]*hp[1]+hp[2]*hp[2]+hp[3]*hp[3];
  #pragma unroll
  for (int d=1; d<64; d<<=1) { s += __shfl_xor(s,d); sq += __shfl_xor(sq,d); }
  float mean = s*(1.f/256.f);
  float rstd = rsqrtf(sq*(1.f/256.f) - mean*mean + LNEPS_);
  float4 wv = ld4(lw+lane*4), bv = ld4(lb+lane*4);
  *(float4*)sp = make_float4(hp[0],hp[1],hp[2],hp[3]);
  short4 o;
  o.x = f2bf((hp[0]-mean)*rstd*wv.x+bv.x);
  o.y = f2bf((hp[1]-mean)*rstd*wv.y+bv.y);
  o.z = f2bf((hp[2]-mean)*rstd*wv.z+bv.z);
  o.w = f2bf((hp[3]-mean)*rstd*wv.w+bv.w);
  *(short4*)(lnmb + (size_t)row*256 + lane*4) = o;
}

// ---------------- slot tail: [MLP2+res | slots-init] + LN_s + qk-GEMM ----------------
// MODE 0: v = hb@w2^T+b2+res(slots), write slots f32+slotsb, LN_s -> qk
// MODE 1: v = mu + sigma*noise (init), write slots f32+slotsb, LN_s -> qk
// MODE 2: v = hb@w2^T+b2+res(slots), write sout (=out_slots) only
// grid 8 blocks (64 slot-rows each), 256 threads.
template<int MODE>
__global__ __launch_bounds__(256) void k_slotend(
    const short* __restrict__ hb, const short* __restrict__ w2b, const float* __restrict__ b2,
    const float* __restrict__ mu, const float* __restrict__ ls, const float* __restrict__ noise,
    const float* __restrict__ res, float* __restrict__ sout, short* __restrict__ slotsb,
    const float* __restrict__ lnsw, const float* __restrict__ lnsb,
    const short* __restrict__ MTb, short* __restrict__ qk) {
  __shared__ short As[64*40];
  __shared__ short Ws[256*40];
  __shared__ short lnS[64*264];
  const int t=threadIdx.x, bm=blockIdx.x;
  const int w=t>>6, lane=t&63, l15=lane&15, lg=lane>>4;
  float v[16][4];
  if (MODE==1) {
    #pragma unroll
    for (int ct=0;ct<16;ct++){
      int col = ct*16+l15;
      float m = mu[col], sg = fmaxf(__expf(ls[col]),1e-6f);
      #pragma unroll
      for (int q=0;q<4;q++){
        int row = bm*64 + w*16 + lg*4 + q;
        v[ct][q] = m + sg*noise[(size_t)row*256+col];
      }
    }
  } else {
    f32x4 acc[16]={};
    for (int k0=0;k0<512;k0+=32){
      __syncthreads();
      *(uint4*)&As[(t>>2)*40+(t&3)*8] = *(const uint4*)&hb[(size_t)(bm*64+(t>>2))*512 + k0 + (t&3)*8];
      // stage 256 rows x 32 k of w2b: 1024 uint4 -> 4 iterations (NOT 8: OOB trampled lnS in R3)
      #pragma unroll
      for (int i=0;i<4;i++){ int idx=t+i*256;
        *(uint4*)&Ws[(idx>>2)*40+(idx&3)*8] = *(const uint4*)&w2b[(size_t)(idx>>2)*512 + k0 + (idx&3)*8]; }
      __syncthreads();
      bf16x8 af = *(const bf16x8*)&As[(w*16+l15)*40+lg*8];
      #pragma unroll
      for (int ct=0;ct<16;ct++){
        bf16x8 bfr = *(const bf16x8*)&Ws[(ct*16+l15)*40+lg*8];
        acc[ct]=__builtin_amdgcn_mfma_f32_16x16x32_bf16(af,bfr,acc[ct],0,0,0);
      }
    }
    #pragma unroll
    for (int ct=0;ct<16;ct++){
      int col = ct*16+l15;
      float bv = b2[col];
      #pragma unroll
      for (int q=0;q<4;q++){
        int row = bm*64 + w*16 + lg*4 + q;
        v[ct][q] = acc[ct][q] + bv + res[(size_t)row*256+col];
      }
    }
  }
  float s[4]={0,0,0,0}, sq[4]={0,0,0,0};
  #pragma unroll
  for (int ct=0;ct<16;ct++)
    #pragma unroll
    for (int q=0;q<4;q++){ s[q]+=v[ct][q]; sq[q]+=v[ct][q]*v[ct][q]; }
  #pragma unroll
  for (int q=0;q<4;q++){
    #pragma unroll
    for (int d=1; d<16; d<<=1){ s[q]+=__shfl_xor(s[q],d,16); sq[q]+=__shfl_xor(sq[q],d,16); }
  }
  #pragma unroll
  for (int ct=0;ct<16;ct++){
    int col = ct*16+l15;
    float lw = (MODE!=2) ? lnsw[col] : 0.f;
    float lb = (MODE!=2) ? lnsb[col] : 0.f;
    #pragma unroll
    for (int q=0;q<4;q++){
      int row = bm*64 + w*16 + lg*4 + q;
      sout[(size_t)row*256+col] = v[ct][q];
      if (MODE!=2){
        float mean = s[q]*(1.f/256.f);
        float rstd = rsqrtf(sq[q]*(1.f/256.f)-mean*mean+LNEPS_);
        slotsb[(size_t)row*256+col] = f2bf(v[ct][q]);
        lnS[(w*16+lg*4+q)*264 + col] = f2bf((v[ct][q]-mean)*rstd*lw+lb);
      }
    }
  }
  if (MODE!=2){
    f32x4 qa[16]={};
    for (int k0=0;k0<256;k0+=32){
      __syncthreads();
      // stage 256 rows x 32 k of MTb: 1024 uint4 -> 4 iterations (NOT 8)
      #pragma unroll
      for (int i=0;i<4;i++){ int idx=t+i*256;
        *(uint4*)&Ws[(idx>>2)*40+(idx&3)*8] = *(const uint4*)&MTb[(size_t)(idx>>2)*256 + k0 + (idx&3)*8]; }
      __syncthreads();
      bf16x8 af = *(const bf16x8*)&lnS[(w*16+l15)*264 + k0 + lg*8];
      #pragma unroll
      for (int ct=0;ct<16;ct++){
        bf16x8 bfr = *(const bf16x8*)&Ws[(ct*16+l15)*40+lg*8];
        qa[ct]=__builtin_amdgcn_mfma_f32_16x16x32_bf16(af,bfr,qa[ct],0,0,0);
      }
    }
    #pragma unroll
    for (int ct=0;ct<16;ct++)
      #pragma unroll
      for (int q=0;q<4;q++)
        qk[(size_t)(bm*64+w*16+lg*4+q)*256 + ct*16+l15] = f2bf(qa[ct][q]);
  }
}

// ---------------- final attn normalization -> d_out ----------------
__global__ __launch_bounds__(256) void k_attn_norm(const float* __restrict__ au,
    const float* __restrict__ cs, float* __restrict__ out) {
  size_t i = ((size_t)blockIdx.x*256 + threadIdx.x)*4;
  float4 v = ld4(au + i);
  int s = (int)(i & 15);
  size_t b = i >> 16;           // 4096*16 elems per batch
  const float* c = cs + b*16 + s;
  float4 o;
  o.x = v.x/(c[0]+EPS_); o.y = v.y/(c[1]+EPS_);
  o.z = v.z/(c[2]+EPS_); o.w = v.w/(c[3]+EPS_);
  *(float4*)(out + i) = o;
}

extern "C" void kernel_launch(void* const* d_in, const int* in_sizes, int n_in,
                              void* d_out, int out_size, void* d_ws, size_t ws_size,
                              hipStream_t stream) {
  const float* inputs   = (const float*)d_in[0];
  const float* token_w  = (const float*)d_in[1];
  const float* noise    = (const float*)d_in[2];
  const float* ln_in_w  = (const float*)d_in[3];
  const float* ln_in_b  = (const float*)d_in[4];
  const float* ln_s_w   = (const float*)d_in[5];
  const float* ln_s_b   = (const float*)d_in[6];
  const float* ln_m_w   = (const float*)d_in[7];
  const float* ln_m_b   = (const float*)d_in[8];
  const float* Wk       = (const float*)d_in[9];
  const float* Wv       = (const float*)d_in[10];
  const float* Wq       = (const float*)d_in[11];
  const float* gru_wih  = (const float*)d_in[12];
  const float* gru_whh  = (const float*)d_in[13];
  const float* gru_bih  = (const float*)d_in[14];
  const float* gru_bhh  = (const float*)d_in[15];
  const float* mlp_w1   = (const float*)d_in[16];
  const float* mlp_b1   = (const float*)d_in[17];
  const float* mlp_w2   = (const float*)d_in[18];
  const float* mlp_b2   = (const float*)d_in[19];
  const float* slots_mu = (const float*)d_in[20];
  const float* slots_ls = (const float*)d_in[21];

  float* out_slots = (float*)d_out;            // [32,16,256]
  float* out_attn  = out_slots + 131072;       // [32,4096,16]

  char* wsb = (char*)d_ws;
  size_t off = 0;
  short* xbf     = (short*)(wsb + off); off += 67108864;   // x bf16 [B,N,D]
  float* attn_un = (float*)(wsb + off); off += 8388608;    // [B,N,S] f32
  float* ux_part = (float*)(wsb + off); off += 8388608;    // [512][16][256] f32
  float* cs_part = (float*)(wsb + off); off += 32768;      // [512][16]
  float* cs_red  = (float*)(wsb + off); off += 2048;       // [B*S]
  short* qk      = (short*)(wsb + off); off += 262144;     // [B*S][D] bf16
  short* uxr     = (short*)(wsb + off); off += 262144;     // reduced ux/colsum, bf16
  short* MTb     = (short*)(wsb + off); off += 131072;     // Wq^T Wk bf16
  short* Mb      = (short*)(wsb + off); off += 393216;     // wih@Wv bf16 [768][256]
  float* gig     = (float*)(wsb + off); off += 3145728;    // [512][1536] f32
  float* slots   = (float*)(wsb + off); off += 524288;     // slots f32
  short* slotsb  = (short*)(wsb + off); off += 262144;     // slots bf16
  short* lnmb    = (short*)(wsb + off); off += 262144;     // LN_m bf16
  short* hb      = (short*)(wsb + off); off += 524288;     // mlp hidden bf16 [512][512]
  short* whhb    = (short*)(wsb + off); off += 393216;
  short* w1b     = (short*)(wsb + off); off += 262144;
  short* w2b     = (short*)(wsb + off); off += 262144;

  k_prep<<<704,256,0,stream>>>(Wq, Wk, gru_wih, Wv, gru_whh, mlp_w1, mlp_w2,
                               MTb, Mb, whhb, w1b, w2b);
  k_slotend<1><<<8,256,0,stream>>>(nullptr, nullptr, nullptr, slots_mu, slots_ls, noise,
                                   nullptr, slots, slotsb, ln_s_w, ln_s_b, MTb, qk);
  for (int it=0; it<3; ++it) {
    if (it==0)
      k3<1,0><<<512,256,0,stream>>>(inputs, ln_in_w, ln_in_b, xbf, qk, token_w,
                                    ux_part, cs_part, attn_un);
    else if (it==1)
      k3<0,0><<<512,256,0,stream>>>(inputs, ln_in_w, ln_in_b, xbf, qk, token_w,
                                    ux_part, cs_part, attn_un);
    else
      k3<0,1><<<512,256,0,stream>>>(inputs, ln_in_w, ln_in_b, xbf, qk, token_w,
                                    ux_part, cs_part, attn_un);
    k_reduce<<<512,256,0,stream>>>(ux_part, cs_part, uxr, cs_red);
    k_gigh<<<dim3(24,8),256,0,stream>>>(uxr, slotsb, Mb, whhb, gru_bih, gru_bhh, gig);
    k_gates<<<128,256,0,stream>>>(gig, ln_m_w, ln_m_b, slots, lnmb);
    k_mlp1<<<dim3(8,8),256,0,stream>>>(lnmb, w1b, mlp_b1, hb);
    if (it<2)
      k_slotend<0><<<8,256,0,stream>>>(hb, w2b, mlp_b2, nullptr, nullptr, nullptr,
                                       slots, slots, slotsb, ln_s_w, ln_s_b, MTb, qk);
    else
      k_slotend<2><<<8,256,0,stream>>>(hb, w2b, mlp_b2, nullptr, nullptr, nullptr,
                                       slots, out_slots, slotsb, ln_s_w, ln_s_b, MTb, qk);
  }
  k_attn_norm<<<2048,256,0,stream>>>(attn_un, cs_red, out_attn);
}